// Round 4
// baseline (4567.470 us; speedup 1.0000x reference)
//
#include <hip/hip_runtime.h>
#include <hip/hip_fp16.h>

#define B_   16
#define T_   4096
#define DIN  256
#define H_   128
#define G3   384   // 3*H

typedef _Float16 half2_t __attribute__((ext_vector_type(2)));
typedef _Float16 half8_t __attribute__((ext_vector_type(8)));
typedef float f32x4 __attribute__((ext_vector_type(4)));

__device__ __forceinline__ float fdot2(unsigned int a, unsigned int b, float c) {
#if __has_builtin(__builtin_amdgcn_fdot2)
  return __builtin_amdgcn_fdot2(__builtin_bit_cast(half2_t, a),
                                __builtin_bit_cast(half2_t, b), c, false);
#else
  const __half2 ha = __builtin_bit_cast(__half2, a);
  const __half2 hb = __builtin_bit_cast(__half2, b);
  return c + __half2float(__low2half(ha)) * __half2float(__low2half(hb))
           + __half2float(__high2half(ha)) * __half2float(__high2half(hb));
#endif
}

__device__ __forceinline__ unsigned int pack2(float x, float y) {
  __half2 h = __floats2half2_rn(x, y);
  return __builtin_bit_cast(unsigned int, h);
}

__device__ __forceinline__ float fsigmoid(float x) {
  return 1.f / (1.f + __expf(-x));
}
__device__ __forceinline__ float ftanh(float x) {
  return 2.f / (1.f + __expf(-2.f * x)) - 1.f;
}

// lgkmcnt-only barrier: LDS ordering without draining global loads/stores.
__device__ __forceinline__ void scan_barrier() {
  asm volatile("s_waitcnt lgkmcnt(0)" ::: "memory");
  __builtin_amdgcn_s_barrier();
  asm volatile("" ::: "memory");
}

__device__ __forceinline__ void wave_lds_fence() {
  asm volatile("s_waitcnt lgkmcnt(0)" ::: "memory");
}

// ---------------------------------------------------------------------------
// Kernel 1: gi[t][j][b] = f16( b_ih[j] + dot(x[b,t,:], w_ih[j,:]) )
// Layout [T][384][16] (batch innermost) so the scan reads dense 8B per gate.
// Block = 8 timesteps x all 16 batches; thread j owns w_ih row j in regs.
// ---------------------------------------------------------------------------
__global__ __launch_bounds__(384, 1) void gi_gemm(
    const float* __restrict__ x, const float* __restrict__ w_ih,
    const float* __restrict__ b_ih, __half* __restrict__ gi) {
  const int j = threadIdx.x;             // 0..383 = gate*128 + col
  const int t0 = blockIdx.x * 8;

  unsigned int wreg[128];                // 256 halves = w_ih row j
  const float* wrow = w_ih + (size_t)j * DIN;
#pragma unroll
  for (int k = 0; k < 128; ++k) {
    float2 w2 = reinterpret_cast<const float2*>(wrow)[k];
    wreg[k] = pack2(w2.x, w2.y);
  }
  const float bias = b_ih[j];

  __shared__ alignas(16) unsigned int xs[16 * 128];  // 16 batches x 256 halves

  for (int tt = 0; tt < 8; ++tt) {
    const int t = t0 + tt;
    __syncthreads();                     // protect xs vs previous reads
    for (int i = j; i < 2048; i += 384) {
      const int b = i >> 7, c2 = i & 127;
      float2 v = reinterpret_cast<const float2*>(x + ((size_t)b * T_ + t) * DIN)[c2];
      xs[i] = pack2(v.x, v.y);
    }
    __syncthreads();

    unsigned int out8[8];
#pragma unroll
    for (int bp = 0; bp < 8; ++bp) {     // batch pairs (static unroll)
      float accp0, accp1;
      {
        const uint4* hp = reinterpret_cast<const uint4*>(xs + (bp * 2 + 0) * 128);
        float a0 = 0.f, a1 = 0.f, a2 = 0.f, a3 = 0.f;
#pragma unroll
        for (int k = 0; k < 32; ++k) {
          uint4 hv = hp[k];
          a0 = fdot2(wreg[4 * k + 0], hv.x, a0);
          a1 = fdot2(wreg[4 * k + 1], hv.y, a1);
          a2 = fdot2(wreg[4 * k + 2], hv.z, a2);
          a3 = fdot2(wreg[4 * k + 3], hv.w, a3);
        }
        accp0 = bias + ((a0 + a1) + (a2 + a3));
      }
      {
        const uint4* hp = reinterpret_cast<const uint4*>(xs + (bp * 2 + 1) * 128);
        float a0 = 0.f, a1 = 0.f, a2 = 0.f, a3 = 0.f;
#pragma unroll
        for (int k = 0; k < 32; ++k) {
          uint4 hv = hp[k];
          a0 = fdot2(wreg[4 * k + 0], hv.x, a0);
          a1 = fdot2(wreg[4 * k + 1], hv.y, a1);
          a2 = fdot2(wreg[4 * k + 2], hv.z, a2);
          a3 = fdot2(wreg[4 * k + 3], hv.w, a3);
        }
        accp1 = bias + ((a0 + a1) + (a2 + a3));
      }
      out8[bp] = pack2(accp0, accp1);
    }
    // dense 32B store: gi[t][j][0..15]
    uint4* dst = reinterpret_cast<uint4*>(gi + ((size_t)t * G3 + j) * 16);
    dst[0] = make_uint4(out8[0], out8[1], out8[2], out8[3]);
    dst[1] = make_uint4(out8[4], out8[5], out8[6], out8[7]);
  }
}

// ---------------------------------------------------------------------------
// Kernel 2: MFMA batch-fused GRU scan. ONE block, 8 waves (512 threads).
// Per step: gh[16x384] = h[16x128] @ W_hh^T via 12 mfma_f32_16x16x32_f16 per
// wave (wave w owns output cols w*16..w*16+15 for all 3 gates). h lives in
// double-buffered XOR-swizzled LDS (f16); D-fragment lanes compute gates
// register-locally (lane holds 4 batch rows of one column).
// ---------------------------------------------------------------------------
__global__ __launch_bounds__(512, 1) void gru_scan(
    const __half* __restrict__ gi, const float* __restrict__ w_hh,
    const float* __restrict__ b_hh, float* __restrict__ out) {
  const int tid = threadIdx.x;
  const int l   = tid & 63;
  const int w   = tid >> 6;            // wave 0..7
  const int l15 = l & 15;
  const int g4  = l >> 4;              // 0..3
  const int col = w * 16 + l15;        // hidden column 0..127
  const int r0  = g4 * 4;              // batch base (D rows)

  // B fragments: wf[g][kt][e] = W_hh[g*128+col][kt*32 + g4*8 + e]  (B = W^T)
  half8_t wf[3][4];
#pragma unroll
  for (int g = 0; g < 3; ++g) {
    const float* wrow = w_hh + (size_t)(g * H_ + col) * H_;
#pragma unroll
    for (int kt = 0; kt < 4; ++kt) {
      const int k0 = kt * 32 + g4 * 8;
      half8_t f;
#pragma unroll
      for (int e = 0; e < 8; ++e) f[e] = (_Float16)wrow[k0 + e];
      wf[g][kt] = f;
    }
  }
  const float biasR = b_hh[col];
  const float biasZ = b_hh[H_ + col];
  const float biasN = b_hh[2 * H_ + col];

  // h buffers: [16 rows][128 cols] f16, 256B row stride, XOR-swizzled
  __shared__ alignas(16) char hA[16 * 256];
  __shared__ alignas(16) char hB[16 * 256];
  for (int i = tid; i < 1024; i += 512)
    reinterpret_cast<unsigned int*>(hA)[i] = 0u;    // h0 = 0

  // A-fragment read offsets: row=l15, 16B at kbyte = kt*64 + g4*16
  int aoff[4];
#pragma unroll
  for (int kt = 0; kt < 4; ++kt)
    aoff[kt] = l15 * 256 + ((kt * 64 + g4 * 16) ^ ((l15 & 7) << 4));
  // h write offsets: row=r0+i, byte col*2
  int woff[4];
#pragma unroll
  for (int i = 0; i < 4; ++i) {
    const int row = r0 + i;
    woff[i] = row * 256 + ((col * 2) ^ ((row & 7) << 4));
  }

  // out pointers per batch row
  float* po[4];
#pragma unroll
  for (int i = 0; i < 4; ++i)
    po[i] = out + ((size_t)(r0 + i) * T_) * H_ + col;

  // gi loads: [t][384][16] halves; lane reads uint2 (4 halves = 4 batches)
  const int offU2[3] = { (0 * H_ + col) * 4 + g4,
                         (1 * H_ + col) * 4 + g4,
                         (2 * H_ + col) * 4 + g4 };
  const uint2* gbase = reinterpret_cast<const uint2*>(gi);
  uint2 pg0[3], pg1[3];
#pragma unroll
  for (int g = 0; g < 3; ++g) pg0[g] = gbase[offU2[g]];            // t=0
  {
    const uint2* g1p = gbase + 1536;
#pragma unroll
    for (int g = 0; g < 3; ++g) pg1[g] = g1p[offU2[g]];            // t=1
  }
  const uint2* gE = gbase + 2 * 1536;   // refill source for even steps (t+2)
  const uint2* gO = gbase + 3 * 1536;   // refill source for odd steps

  float hp0 = 0.f, hp1 = 0.f, hp2 = 0.f, hp3 = 0.f;
  scan_barrier();

#define GATE(i, HP, FR, FZ, FN, TB, WBUF)                                   \
  {                                                                         \
    const float rg = fsigmoid(FR + accR[i]);                                \
    const float zg = fsigmoid(FZ + accZ[i]);                                \
    const float ng = ftanh(fmaf(rg, accN[i], FN));                          \
    const float h  = fmaf(zg, HP - ng, ng);                                 \
    HP = h;                                                                 \
    po[i][TB] = h;                                                          \
    *reinterpret_cast<__half*>((WBUF) + woff[i]) = __float2half(h);         \
  }

#define STEP(TT, PG, RBUF, WBUF, GPTR)                                      \
  {                                                                         \
    const half8_t a0 = *reinterpret_cast<const half8_t*>((RBUF) + aoff[0]); \
    const half8_t a1 = *reinterpret_cast<const half8_t*>((RBUF) + aoff[1]); \
    const half8_t a2 = *reinterpret_cast<const half8_t*>((RBUF) + aoff[2]); \
    const half8_t a3 = *reinterpret_cast<const half8_t*>((RBUF) + aoff[3]); \
    f32x4 accR = {biasR, biasR, biasR, biasR};                              \
    f32x4 accZ = {biasZ, biasZ, biasZ, biasZ};                              \
    f32x4 accN = {biasN, biasN, biasN, biasN};                              \
    accR = __builtin_amdgcn_mfma_f32_16x16x32_f16(a0, wf[0][0], accR,0,0,0);\
    accZ = __builtin_amdgcn_mfma_f32_16x16x32_f16(a0, wf[1][0], accZ,0,0,0);\
    accN = __builtin_amdgcn_mfma_f32_16x16x32_f16(a0, wf[2][0], accN,0,0,0);\
    accR = __builtin_amdgcn_mfma_f32_16x16x32_f16(a1, wf[0][1], accR,0,0,0);\
    accZ = __builtin_amdgcn_mfma_f32_16x16x32_f16(a1, wf[1][1], accZ,0,0,0);\
    accN = __builtin_amdgcn_mfma_f32_16x16x32_f16(a1, wf[2][1], accN,0,0,0);\
    accR = __builtin_amdgcn_mfma_f32_16x16x32_f16(a2, wf[0][2], accR,0,0,0);\
    accZ = __builtin_amdgcn_mfma_f32_16x16x32_f16(a2, wf[1][2], accZ,0,0,0);\
    accN = __builtin_amdgcn_mfma_f32_16x16x32_f16(a2, wf[2][2], accN,0,0,0);\
    accR = __builtin_amdgcn_mfma_f32_16x16x32_f16(a3, wf[0][3], accR,0,0,0);\
    accZ = __builtin_amdgcn_mfma_f32_16x16x32_f16(a3, wf[1][3], accZ,0,0,0);\
    accN = __builtin_amdgcn_mfma_f32_16x16x32_f16(a3, wf[2][3], accN,0,0,0);\
    const float2 fr01 = __half22float2(__builtin_bit_cast(__half2, PG[0].x));\
    const float2 fr23 = __half22float2(__builtin_bit_cast(__half2, PG[0].y));\
    const float2 fz01 = __half22float2(__builtin_bit_cast(__half2, PG[1].x));\
    const float2 fz23 = __half22float2(__builtin_bit_cast(__half2, PG[1].y));\
    const float2 fn01 = __half22float2(__builtin_bit_cast(__half2, PG[2].x));\
    const float2 fn23 = __half22float2(__builtin_bit_cast(__half2, PG[2].y));\
    if ((TT) + 2 < T_) {   /* refill same named regs for TT+2 */            \
      PG[0] = (GPTR)[offU2[0]];                                             \
      PG[1] = (GPTR)[offU2[1]];                                             \
      PG[2] = (GPTR)[offU2[2]];                                             \
    }                                                                       \
    GPTR += 3072;                                                           \
    const size_t tb = (size_t)(TT) * H_;                                    \
    GATE(0, hp0, fr01.x, fz01.x, fn01.x, tb, WBUF)                          \
    GATE(1, hp1, fr01.y, fz01.y, fn01.y, tb, WBUF)                          \
    GATE(2, hp2, fr23.x, fz23.x, fn23.x, tb, WBUF)                          \
    GATE(3, hp3, fr23.y, fz23.y, fn23.y, tb, WBUF)                          \
    scan_barrier();                                                         \
  }

  for (int t = 0; t < T_; t += 2) {
    STEP(t,     pg0, hA, hB, gE)
    STEP(t + 1, pg1, hB, hA, gO)
  }
#undef STEP
#undef GATE
}

// ---------------------------------------------------------------------------
// Kernel 3: y = h @ w_proj.T + b_proj, then LayerNorm. In-place on io.
// ---------------------------------------------------------------------------
#define PROJ_ROWS 64
__global__ __launch_bounds__(64, 1) void proj_ln(
    float* __restrict__ io, const float* __restrict__ w_proj,
    const float* __restrict__ b_proj, const float* __restrict__ gamma,
    const float* __restrict__ beta) {
  const int lane = threadIdx.x;
  const int row0 = blockIdx.x * PROJ_ROWS;
  const int jA = lane, jB = lane + 64;

  unsigned int wa[64], wb[64];
#pragma unroll
  for (int k = 0; k < 64; ++k) {
    float2 v = reinterpret_cast<const float2*>(w_proj + (size_t)jA * H_)[k];
    wa[k] = pack2(v.x, v.y);
  }
#pragma unroll
  for (int k = 0; k < 64; ++k) {
    float2 v = reinterpret_cast<const float2*>(w_proj + (size_t)jB * H_)[k];
    wb[k] = pack2(v.x, v.y);
  }
  const float bA = b_proj[jA], bB = b_proj[jB];
  const float gmA = gamma[jA], gmB = gamma[jB];
  const float btA = beta[jA], btB = beta[jB];

  __shared__ alignas(16) unsigned int hbuf[64];  // 128 halves: one row

  for (int r = 0; r < PROJ_ROWS; ++r) {
    float* rowp = io + (size_t)(row0 + r) * H_;
    float2 v = reinterpret_cast<float2*>(rowp)[lane];
    hbuf[lane] = pack2(v.x, v.y);
    wave_lds_fence();

    float aA = bA, aB = bB;
    const uint4* hp = reinterpret_cast<const uint4*>(hbuf);
#pragma unroll
    for (int k = 0; k < 16; ++k) {
      uint4 hv = hp[k];
      aA = fdot2(wa[4 * k + 0], hv.x, aA);
      aA = fdot2(wa[4 * k + 1], hv.y, aA);
      aA = fdot2(wa[4 * k + 2], hv.z, aA);
      aA = fdot2(wa[4 * k + 3], hv.w, aA);
      aB = fdot2(wb[4 * k + 0], hv.x, aB);
      aB = fdot2(wb[4 * k + 1], hv.y, aB);
      aB = fdot2(wb[4 * k + 2], hv.z, aB);
      aB = fdot2(wb[4 * k + 3], hv.w, aB);
    }

    float s = aA + aB;
    float q = aA * aA + aB * aB;
#pragma unroll
    for (int m = 1; m < 64; m <<= 1) {
      s += __shfl_xor(s, m, 64);
      q += __shfl_xor(q, m, 64);
    }
    const float mu = s * (1.f / 128.f);
    const float var = q * (1.f / 128.f) - mu * mu;
    const float rs = rsqrtf(var + 1e-5f);
    rowp[lane]      = (aA - mu) * rs * gmA + btA;
    rowp[lane + 64] = (aB - mu) * rs * gmB + btB;
    wave_lds_fence();
  }
}

// ---------------------------------------------------------------------------
extern "C" void kernel_launch(void* const* d_in, const int* in_sizes, int n_in,
                              void* d_out, int out_size, void* d_ws, size_t ws_size,
                              hipStream_t stream) {
  const float* x      = (const float*)d_in[0];
  const float* w_ih   = (const float*)d_in[1];
  const float* w_hh   = (const float*)d_in[2];
  const float* b_ih   = (const float*)d_in[3];
  const float* b_hh   = (const float*)d_in[4];
  const float* w_proj = (const float*)d_in[5];
  const float* b_proj = (const float*)d_in[6];
  const float* gamma  = (const float*)d_in[7];
  const float* beta   = (const float*)d_in[8];

  float* out = (float*)d_out;
  __half* gi = (__half*)d_ws;            // [T][384][16] f16 = 48 MB scratch

  gi_gemm<<<T_ / 8, 384, 0, stream>>>(x, w_ih, b_ih, gi);
  gru_scan<<<1, 512, 0, stream>>>(gi, w_hh, b_hh, out);
  proj_ln<<<(B_ * T_) / PROJ_ROWS, 64, 0, stream>>>(out, w_proj, b_proj, gamma, beta);
}

// Round 5
// 2520.884 us; speedup vs baseline: 1.8119x; 1.8119x over previous
//
#include <hip/hip_runtime.h>
#include <hip/hip_fp16.h>

#define B_   16
#define T_   4096
#define DIN  256
#define H_   128
#define G3   384   // 3*H

typedef _Float16 half2_t __attribute__((ext_vector_type(2)));

__device__ __forceinline__ float fdot2(unsigned int a, unsigned int b, float c) {
#if __has_builtin(__builtin_amdgcn_fdot2)
  return __builtin_amdgcn_fdot2(__builtin_bit_cast(half2_t, a),
                                __builtin_bit_cast(half2_t, b), c, false);
#else
  const __half2 ha = __builtin_bit_cast(__half2, a);
  const __half2 hb = __builtin_bit_cast(__half2, b);
  return c + __half2float(__low2half(ha)) * __half2float(__low2half(hb))
           + __half2float(__high2half(ha)) * __half2float(__high2half(hb));
#endif
}

__device__ __forceinline__ unsigned int pack2(float x, float y) {
  __half2 h = __floats2half2_rn(x, y);
  return __builtin_bit_cast(unsigned int, h);
}

__device__ __forceinline__ float fsigmoid(float x) {
  return 1.f / (1.f + __expf(-x));
}
__device__ __forceinline__ float ftanh(float x) {
  return 2.f / (1.f + __expf(-2.f * x)) - 1.f;
}

// lgkmcnt-only barrier: LDS ordering without draining global loads/stores.
__device__ __forceinline__ void scan_barrier() {
  asm volatile("s_waitcnt lgkmcnt(0)" ::: "memory");
  __builtin_amdgcn_s_barrier();
  asm volatile("" ::: "memory");
}

__device__ __forceinline__ void barrier_lds() {
  __builtin_amdgcn_sched_barrier(0);
  asm volatile("s_waitcnt lgkmcnt(0)" ::: "memory");
  __builtin_amdgcn_s_barrier();
  __builtin_amdgcn_sched_barrier(0);
}

__device__ __forceinline__ void wave_lds_fence() {
  asm volatile("s_waitcnt lgkmcnt(0)" ::: "memory");
}

// ---------------------------------------------------------------------------
// Kernel 1: gi[r, j] = f16( b_ih[j] + dot(x[r, :], w_ih[j, :]) ), r = b*T+t.
// ---------------------------------------------------------------------------
__global__ __launch_bounds__(384, 1) void gi_gemm(
    const float* __restrict__ x, const float* __restrict__ w_ih,
    const float* __restrict__ b_ih, __half* __restrict__ gi) {
  const int j = threadIdx.x;             // 0..383 : output gate-row
  const int rbase = blockIdx.x * 128;    // 128 x-rows per block

  unsigned int wreg[128];                // 256 halves = w_ih row j
  const float* wrow = w_ih + (size_t)j * DIN;
#pragma unroll
  for (int k = 0; k < 128; ++k) {
    float2 w2 = reinterpret_cast<const float2*>(wrow)[k];
    wreg[k] = pack2(w2.x, w2.y);
  }
  const float bias = b_ih[j];

  __shared__ alignas(16) unsigned int xs[16 * 128];  // 16 rows x 256 halves

  for (int c = 0; c < 8; ++c) {          // 8 chunks of 16 rows
    barrier_lds();                       // protect xs vs previous chunk reads
    const int row0 = rbase + c * 16;
    for (int i = j; i < 16 * 128; i += 384) {
      const int r = i >> 7, col = i & 127;
      float2 v = reinterpret_cast<const float2*>(x + (size_t)(row0 + r) * DIN)[col];
      xs[i] = pack2(v.x, v.y);
    }
    barrier_lds();
    for (int r = 0; r < 16; ++r) {
      float a0 = 0.f, a1 = 0.f, a2 = 0.f, a3 = 0.f;
      const uint4* hp = reinterpret_cast<const uint4*>(xs + r * 128);
#pragma unroll
      for (int k = 0; k < 32; ++k) {
        uint4 hv = hp[k];                // uniform addr -> LDS broadcast
        a0 = fdot2(wreg[4 * k + 0], hv.x, a0);
        a1 = fdot2(wreg[4 * k + 1], hv.y, a1);
        a2 = fdot2(wreg[4 * k + 2], hv.z, a2);
        a3 = fdot2(wreg[4 * k + 3], hv.w, a3);
      }
      const float acc = bias + ((a0 + a1) + (a2 + a3));
      gi[(size_t)(row0 + r) * G3 + j] = __float2half(acc);
    }
  }
}

// ---------------------------------------------------------------------------
// Kernel 2: GRU scan. 16 blocks (1/batch) x 256 threads (4 waves, 1/SIMD).
// Lane (w, l): col c = w*32 + (l&31), K-half = l>>5. Each lane computes 3
// half-dots (96 dot2); full sums via one __shfl_xor(32) per gate; both halves
// redundantly run the gate math for col c (uniform, no divergence); half-0
// lanes store h. h in double-buffered LDS f16 (half0 @0B, half1 @144B ->
// conflict-free b128 reads). One lgkm-only barrier per step. gi prefetched
// 4 steps deep in statically-named registers.
// ---------------------------------------------------------------------------
__global__ __launch_bounds__(256, 1) void gru_scan(
    const __half* __restrict__ gi, const float* __restrict__ w_hh,
    const float* __restrict__ b_hh, float* __restrict__ out) {
  const int b   = blockIdx.x;
  const int tid = threadIdx.x;
  const int l   = tid & 63;
  const int w   = tid >> 6;              // wave 0..3
  const int half = l >> 5;               // K-half 0/1
  const int c   = w * 32 + (l & 31);     // hidden column 0..127

  // Weights: rows {c, 128+c, 256+c}, K-range [half*64, half*64+64), f16x2.
  unsigned int wgt[3][32];
#pragma unroll
  for (int g = 0; g < 3; ++g) {
    const float* row = w_hh + (size_t)(g * H_ + c) * H_ + half * 64;
#pragma unroll
    for (int k = 0; k < 32; ++k) {
      float2 a = reinterpret_cast<const float2*>(row)[k];
      wgt[g][k] = pack2(a.x, a.y);
    }
  }
  const float br = b_hh[c], bz = b_hh[H_ + c], bn = b_hh[2 * H_ + c];

  // h buffers: half0 = h[0..63] at bytes 0..127; half1 = h[64..127] at
  // bytes 144..271 (offset 144 staggers banks: read k: banks 4k vs 4k+4).
  __shared__ alignas(16) char hA[288];
  __shared__ alignas(16) char hB[288];
  if (tid < 72) reinterpret_cast<unsigned int*>(hA)[tid] = 0u;  // h0 = 0

  const int abase = half * 144;          // this lane's K-half read base
  const int woff  = (c < 64) ? (c * 2) : (144 + (c - 64) * 2);

  const __half* gp = gi + (size_t)b * T_ * G3;
  float* po = out + ((size_t)b * T_) * H_ + c;
  const int o0 = c, o1 = H_ + c, o2 = 2 * H_ + c;

  // 4-deep prefetch: raw __half regs (convert at use), statically named.
  __half pa0 = gp[o0],          pz0 = gp[o1],          pn0 = gp[o2];
  __half pa1 = gp[G3 + o0],     pz1 = gp[G3 + o1],     pn1 = gp[G3 + o2];
  __half pa2 = gp[2 * G3 + o0], pz2 = gp[2 * G3 + o1], pn2 = gp[2 * G3 + o2];
  __half pa3 = gp[3 * G3 + o0], pz3 = gp[3 * G3 + o1], pn3 = gp[3 * G3 + o2];
  const __half* r0 = gp + 4 * G3;        // refill sources, one per phase
  const __half* r1 = gp + 5 * G3;
  const __half* r2 = gp + 6 * G3;
  const __half* r3 = gp + 7 * G3;

  float hp = 0.f;                        // previous h for col c
  scan_barrier();

#define STEP(TT, PA, PZ, PN, RB, WB, RP)                                    \
  {                                                                         \
    const float ga = __half2float(PA);                                      \
    const float gz = __half2float(PZ);                                      \
    const float gn = __half2float(PN);                                      \
    if ((TT) + 4 < T_) {  /* refill same named regs for TT+4 */             \
      PA = (RP)[o0]; PZ = (RP)[o1]; PN = (RP)[o2];                          \
    }                                                                       \
    RP += 4 * G3;                                                           \
    float aR = 0.f, aZ = 0.f, aN = 0.f;                                     \
    _Pragma("unroll")                                                       \
    for (int k = 0; k < 8; ++k) {                                           \
      const uint4 hv = *reinterpret_cast<const uint4*>((RB) + abase + k * 16);\
      aR = fdot2(wgt[0][4 * k + 0], hv.x, aR);                              \
      aR = fdot2(wgt[0][4 * k + 1], hv.y, aR);                              \
      aR = fdot2(wgt[0][4 * k + 2], hv.z, aR);                              \
      aR = fdot2(wgt[0][4 * k + 3], hv.w, aR);                              \
      aZ = fdot2(wgt[1][4 * k + 0], hv.x, aZ);                              \
      aZ = fdot2(wgt[1][4 * k + 1], hv.y, aZ);                              \
      aZ = fdot2(wgt[1][4 * k + 2], hv.z, aZ);                              \
      aZ = fdot2(wgt[1][4 * k + 3], hv.w, aZ);                              \
      aN = fdot2(wgt[2][4 * k + 0], hv.x, aN);                              \
      aN = fdot2(wgt[2][4 * k + 1], hv.y, aN);                              \
      aN = fdot2(wgt[2][4 * k + 2], hv.z, aN);                              \
      aN = fdot2(wgt[2][4 * k + 3], hv.w, aN);                              \
    }                                                                       \
    const float fR = br + aR + __shfl_xor(aR, 32, 64);                      \
    const float fZ = bz + aZ + __shfl_xor(aZ, 32, 64);                      \
    const float fN = bn + aN + __shfl_xor(aN, 32, 64);                      \
    const float rg = fsigmoid(ga + fR);                                     \
    const float zg = fsigmoid(gz + fZ);                                     \
    const float ng = ftanh(fmaf(rg, fN, gn));                               \
    const float h  = fmaf(zg, hp - ng, ng);                                 \
    hp = h;                                                                 \
    if (half == 0) {                                                        \
      po[(size_t)(TT) * H_] = h;                                            \
      *reinterpret_cast<__half*>((WB) + woff) = __float2half(h);            \
    }                                                                       \
    scan_barrier();                                                         \
  }

  for (int t = 0; t < T_; t += 4) {
    STEP(t,     pa0, pz0, pn0, hA, hB, r0)
    STEP(t + 1, pa1, pz1, pn1, hB, hA, r1)
    STEP(t + 2, pa2, pz2, pn2, hA, hB, r2)
    STEP(t + 3, pa3, pz3, pn3, hB, hA, r3)
  }
#undef STEP
}

// ---------------------------------------------------------------------------
// Kernel 3: y = h @ w_proj.T + b_proj, then LayerNorm. In-place on io.
// ---------------------------------------------------------------------------
#define PROJ_ROWS 64
__global__ __launch_bounds__(64, 1) void proj_ln(
    float* __restrict__ io, const float* __restrict__ w_proj,
    const float* __restrict__ b_proj, const float* __restrict__ gamma,
    const float* __restrict__ beta) {
  const int lane = threadIdx.x;
  const int row0 = blockIdx.x * PROJ_ROWS;
  const int jA = lane, jB = lane + 64;

  unsigned int wa[64], wb[64];
#pragma unroll
  for (int k = 0; k < 64; ++k) {
    float2 v = reinterpret_cast<const float2*>(w_proj + (size_t)jA * H_)[k];
    wa[k] = pack2(v.x, v.y);
  }
#pragma unroll
  for (int k = 0; k < 64; ++k) {
    float2 v = reinterpret_cast<const float2*>(w_proj + (size_t)jB * H_)[k];
    wb[k] = pack2(v.x, v.y);
  }
  const float bA = b_proj[jA], bB = b_proj[jB];
  const float gmA = gamma[jA], gmB = gamma[jB];
  const float btA = beta[jA], btB = beta[jB];

  __shared__ alignas(16) unsigned int hbuf[64];  // 128 halves: one row

  for (int r = 0; r < PROJ_ROWS; ++r) {
    float* rowp = io + (size_t)(row0 + r) * H_;
    float2 v = reinterpret_cast<float2*>(rowp)[lane];
    hbuf[lane] = pack2(v.x, v.y);
    wave_lds_fence();

    float aA = bA, aB = bB;
    const uint4* hp = reinterpret_cast<const uint4*>(hbuf);
#pragma unroll
    for (int k = 0; k < 16; ++k) {
      uint4 hv = hp[k];
      aA = fdot2(wa[4 * k + 0], hv.x, aA);
      aA = fdot2(wa[4 * k + 1], hv.y, aA);
      aA = fdot2(wa[4 * k + 2], hv.z, aA);
      aA = fdot2(wa[4 * k + 3], hv.w, aA);
      aB = fdot2(wb[4 * k + 0], hv.x, aB);
      aB = fdot2(wb[4 * k + 1], hv.y, aB);
      aB = fdot2(wb[4 * k + 2], hv.z, aB);
      aB = fdot2(wb[4 * k + 3], hv.w, aB);
    }

    float s = aA + aB;
    float q = aA * aA + aB * aB;
#pragma unroll
    for (int m = 1; m < 64; m <<= 1) {
      s += __shfl_xor(s, m, 64);
      q += __shfl_xor(q, m, 64);
    }
    const float mu = s * (1.f / 128.f);
    const float var = q * (1.f / 128.f) - mu * mu;
    const float rs = rsqrtf(var + 1e-5f);
    rowp[lane]      = (aA - mu) * rs * gmA + btA;
    rowp[lane + 64] = (aB - mu) * rs * gmB + btB;
    wave_lds_fence();
  }
}

// ---------------------------------------------------------------------------
extern "C" void kernel_launch(void* const* d_in, const int* in_sizes, int n_in,
                              void* d_out, int out_size, void* d_ws, size_t ws_size,
                              hipStream_t stream) {
  const float* x      = (const float*)d_in[0];
  const float* w_ih   = (const float*)d_in[1];
  const float* w_hh   = (const float*)d_in[2];
  const float* b_ih   = (const float*)d_in[3];
  const float* b_hh   = (const float*)d_in[4];
  const float* w_proj = (const float*)d_in[5];
  const float* b_proj = (const float*)d_in[6];
  const float* gamma  = (const float*)d_in[7];
  const float* beta   = (const float*)d_in[8];

  float* out = (float*)d_out;
  __half* gi = (__half*)d_ws;            // [B*T][384] f16 = 48 MB scratch

  gi_gemm<<<512, 384, 0, stream>>>(x, w_ih, b_ih, gi);
  gru_scan<<<B_, 256, 0, stream>>>(gi, w_hh, b_hh, out);
  proj_ln<<<(B_ * T_) / PROJ_ROWS, 64, 0, stream>>>(out, w_proj, b_proj, gamma, beta);
}

// Round 6
// 2520.247 us; speedup vs baseline: 1.8123x; 1.0003x over previous
//
#include <hip/hip_runtime.h>
#include <hip/hip_fp16.h>

#define B_   16
#define T_   4096
#define DIN  256
#define H_   128
#define G3   384   // 3*H

typedef _Float16 half2_t __attribute__((ext_vector_type(2)));

__device__ __forceinline__ float fdot2(unsigned int a, unsigned int b, float c) {
#if __has_builtin(__builtin_amdgcn_fdot2)
  return __builtin_amdgcn_fdot2(__builtin_bit_cast(half2_t, a),
                                __builtin_bit_cast(half2_t, b), c, false);
#else
  const __half2 ha = __builtin_bit_cast(__half2, a);
  const __half2 hb = __builtin_bit_cast(__half2, b);
  return c + __half2float(__low2half(ha)) * __half2float(__low2half(hb))
           + __half2float(__high2half(ha)) * __half2float(__high2half(hb));
#endif
}

__device__ __forceinline__ unsigned int pack2(float x, float y) {
  __half2 h = __floats2half2_rn(x, y);
  return __builtin_bit_cast(unsigned int, h);
}

__device__ __forceinline__ float fsigmoid(float x) {
  return 1.f / (1.f + __expf(-x));
}
__device__ __forceinline__ float ftanh(float x) {
  return 2.f / (1.f + __expf(-2.f * x)) - 1.f;
}

// lgkmcnt-only barrier: LDS ordering without draining global loads/stores.
__device__ __forceinline__ void scan_barrier() {
  asm volatile("s_waitcnt lgkmcnt(0)" ::: "memory");
  __builtin_amdgcn_s_barrier();
  asm volatile("" ::: "memory");
}

__device__ __forceinline__ void barrier_lds() {
  __builtin_amdgcn_sched_barrier(0);
  asm volatile("s_waitcnt lgkmcnt(0)" ::: "memory");
  __builtin_amdgcn_s_barrier();
  __builtin_amdgcn_sched_barrier(0);
}

__device__ __forceinline__ void wave_lds_fence() {
  asm volatile("s_waitcnt lgkmcnt(0)" ::: "memory");
}

// ---------------------------------------------------------------------------
// Kernel 1: gi[r, j] = f16( b_ih[j] + dot(x[r, :], w_ih[j, :]) ), r = b*T+t.
// ---------------------------------------------------------------------------
__global__ __launch_bounds__(384, 1) void gi_gemm(
    const float* __restrict__ x, const float* __restrict__ w_ih,
    const float* __restrict__ b_ih, __half* __restrict__ gi) {
  const int j = threadIdx.x;             // 0..383 : output gate-row
  const int rbase = blockIdx.x * 128;    // 128 x-rows per block

  unsigned int wreg[128];                // 256 halves = w_ih row j
  const float* wrow = w_ih + (size_t)j * DIN;
#pragma unroll
  for (int k = 0; k < 128; ++k) {
    float2 w2 = reinterpret_cast<const float2*>(wrow)[k];
    wreg[k] = pack2(w2.x, w2.y);
  }
  const float bias = b_ih[j];

  __shared__ alignas(16) unsigned int xs[16 * 128];  // 16 rows x 256 halves

  for (int c = 0; c < 8; ++c) {          // 8 chunks of 16 rows
    barrier_lds();                       // protect xs vs previous chunk reads
    const int row0 = rbase + c * 16;
    for (int i = j; i < 16 * 128; i += 384) {
      const int r = i >> 7, col = i & 127;
      float2 v = reinterpret_cast<const float2*>(x + (size_t)(row0 + r) * DIN)[col];
      xs[i] = pack2(v.x, v.y);
    }
    barrier_lds();
    for (int r = 0; r < 16; ++r) {
      float a0 = 0.f, a1 = 0.f, a2 = 0.f, a3 = 0.f;
      const uint4* hp = reinterpret_cast<const uint4*>(xs + r * 128);
#pragma unroll
      for (int k = 0; k < 32; ++k) {
        uint4 hv = hp[k];                // uniform addr -> LDS broadcast
        a0 = fdot2(wreg[4 * k + 0], hv.x, a0);
        a1 = fdot2(wreg[4 * k + 1], hv.y, a1);
        a2 = fdot2(wreg[4 * k + 2], hv.z, a2);
        a3 = fdot2(wreg[4 * k + 3], hv.w, a3);
      }
      const float acc = bias + ((a0 + a1) + (a2 + a3));
      gi[(size_t)(row0 + r) * G3 + j] = __float2half(acc);
    }
  }
}

// ---------------------------------------------------------------------------
// Kernel 2: GRU scan. 16 blocks (1/batch) x 256 threads (4 waves, 1/SIMD).
// Lane (w, l): col c = w*32 + (l&31), K-half = l>>5. Each lane computes 3
// half-dots (96 dot2); full sums via one __shfl_xor(32) per gate; both halves
// redundantly run the gate math for col c (uniform, no divergence); half-0
// lanes store h. h in double-buffered LDS f16 (half0 @0B, half1 @144B ->
// conflict-free b128 reads). One lgkm-only barrier per step. gi prefetched
// 4 steps deep in statically-named registers.
// ---------------------------------------------------------------------------
__global__ __launch_bounds__(256, 1) void gru_scan(
    const __half* __restrict__ gi, const float* __restrict__ w_hh,
    const float* __restrict__ b_hh, float* __restrict__ out) {
  const int b   = blockIdx.x;
  const int tid = threadIdx.x;
  const int l   = tid & 63;
  const int w   = tid >> 6;              // wave 0..3
  const int half = l >> 5;               // K-half 0/1
  const int c   = w * 32 + (l & 31);     // hidden column 0..127

  // Weights: rows {c, 128+c, 256+c}, K-range [half*64, half*64+64), f16x2.
  unsigned int wgt[3][32];
#pragma unroll
  for (int g = 0; g < 3; ++g) {
    const float* row = w_hh + (size_t)(g * H_ + c) * H_ + half * 64;
#pragma unroll
    for (int k = 0; k < 32; ++k) {
      float2 a = reinterpret_cast<const float2*>(row)[k];
      wgt[g][k] = pack2(a.x, a.y);
    }
  }
  const float br = b_hh[c], bz = b_hh[H_ + c], bn = b_hh[2 * H_ + c];

  // h buffers: half0 = h[0..63] at bytes 0..127; half1 = h[64..127] at
  // bytes 144..271 (offset 144 staggers banks: read k: banks 4k vs 4k+4).
  __shared__ alignas(16) char hA[288];
  __shared__ alignas(16) char hB[288];
  if (tid < 72) reinterpret_cast<unsigned int*>(hA)[tid] = 0u;  // h0 = 0

  const int abase = half * 144;          // this lane's K-half read base
  const int woff  = (c < 64) ? (c * 2) : (144 + (c - 64) * 2);

  const __half* gp = gi + (size_t)b * T_ * G3;
  float* po = out + ((size_t)b * T_) * H_ + c;
  const int o0 = c, o1 = H_ + c, o2 = 2 * H_ + c;

  // 4-deep prefetch: raw __half regs (convert at use), statically named.
  __half pa0 = gp[o0],          pz0 = gp[o1],          pn0 = gp[o2];
  __half pa1 = gp[G3 + o0],     pz1 = gp[G3 + o1],     pn1 = gp[G3 + o2];
  __half pa2 = gp[2 * G3 + o0], pz2 = gp[2 * G3 + o1], pn2 = gp[2 * G3 + o2];
  __half pa3 = gp[3 * G3 + o0], pz3 = gp[3 * G3 + o1], pn3 = gp[3 * G3 + o2];
  const __half* r0 = gp + 4 * G3;        // refill sources, one per phase
  const __half* r1 = gp + 5 * G3;
  const __half* r2 = gp + 6 * G3;
  const __half* r3 = gp + 7 * G3;

  float hp = 0.f;                        // previous h for col c
  scan_barrier();

#define STEP(TT, PA, PZ, PN, RB, WB, RP)                                    \
  {                                                                         \
    const float ga = __half2float(PA);                                      \
    const float gz = __half2float(PZ);                                      \
    const float gn = __half2float(PN);                                      \
    if ((TT) + 4 < T_) {  /* refill same named regs for TT+4 */             \
      PA = (RP)[o0]; PZ = (RP)[o1]; PN = (RP)[o2];                          \
    }                                                                       \
    RP += 4 * G3;                                                           \
    float aR = 0.f, aZ = 0.f, aN = 0.f;                                     \
    _Pragma("unroll")                                                       \
    for (int k = 0; k < 8; ++k) {                                           \
      const uint4 hv = *reinterpret_cast<const uint4*>((RB) + abase + k * 16);\
      aR = fdot2(wgt[0][4 * k + 0], hv.x, aR);                              \
      aR = fdot2(wgt[0][4 * k + 1], hv.y, aR);                              \
      aR = fdot2(wgt[0][4 * k + 2], hv.z, aR);                              \
      aR = fdot2(wgt[0][4 * k + 3], hv.w, aR);                              \
      aZ = fdot2(wgt[1][4 * k + 0], hv.x, aZ);                              \
      aZ = fdot2(wgt[1][4 * k + 1], hv.y, aZ);                              \
      aZ = fdot2(wgt[1][4 * k + 2], hv.z, aZ);                              \
      aZ = fdot2(wgt[1][4 * k + 3], hv.w, aZ);                              \
      aN = fdot2(wgt[2][4 * k + 0], hv.x, aN);                              \
      aN = fdot2(wgt[2][4 * k + 1], hv.y, aN);                              \
      aN = fdot2(wgt[2][4 * k + 2], hv.z, aN);                              \
      aN = fdot2(wgt[2][4 * k + 3], hv.w, aN);                              \
    }                                                                       \
    const float fR = br + aR + __shfl_xor(aR, 32, 64);                      \
    const float fZ = bz + aZ + __shfl_xor(aZ, 32, 64);                      \
    const float fN = bn + aN + __shfl_xor(aN, 32, 64);                      \
    const float rg = fsigmoid(ga + fR);                                     \
    const float zg = fsigmoid(gz + fZ);                                     \
    const float ng = ftanh(fmaf(rg, fN, gn));                               \
    const float h  = fmaf(zg, hp - ng, ng);                                 \
    hp = h;                                                                 \
    if (half == 0) {                                                        \
      po[(size_t)(TT) * H_] = h;                                            \
      *reinterpret_cast<__half*>((WB) + woff) = __float2half(h);            \
    }                                                                       \
    scan_barrier();                                                         \
  }

  for (int t = 0; t < T_; t += 4) {
    STEP(t,     pa0, pz0, pn0, hA, hB, r0)
    STEP(t + 1, pa1, pz1, pn1, hB, hA, r1)
    STEP(t + 2, pa2, pz2, pn2, hA, hB, r2)
    STEP(t + 3, pa3, pz3, pn3, hB, hA, r3)
  }
#undef STEP
}

// ---------------------------------------------------------------------------
// Kernel 3: y = h @ w_proj.T + b_proj, then LayerNorm. In-place on io.
// ---------------------------------------------------------------------------
#define PROJ_ROWS 64
__global__ __launch_bounds__(64, 1) void proj_ln(
    float* __restrict__ io, const float* __restrict__ w_proj,
    const float* __restrict__ b_proj, const float* __restrict__ gamma,
    const float* __restrict__ beta) {
  const int lane = threadIdx.x;
  const int row0 = blockIdx.x * PROJ_ROWS;
  const int jA = lane, jB = lane + 64;

  unsigned int wa[64], wb[64];
#pragma unroll
  for (int k = 0; k < 64; ++k) {
    float2 v = reinterpret_cast<const float2*>(w_proj + (size_t)jA * H_)[k];
    wa[k] = pack2(v.x, v.y);
  }
#pragma unroll
  for (int k = 0; k < 64; ++k) {
    float2 v = reinterpret_cast<const float2*>(w_proj + (size_t)jB * H_)[k];
    wb[k] = pack2(v.x, v.y);
  }
  const float bA = b_proj[jA], bB = b_proj[jB];
  const float gmA = gamma[jA], gmB = gamma[jB];
  const float btA = beta[jA], btB = beta[jB];

  __shared__ alignas(16) unsigned int hbuf[64];  // 128 halves: one row

  for (int r = 0; r < PROJ_ROWS; ++r) {
    float* rowp = io + (size_t)(row0 + r) * H_;
    float2 v = reinterpret_cast<float2*>(rowp)[lane];
    hbuf[lane] = pack2(v.x, v.y);
    wave_lds_fence();

    float aA = bA, aB = bB;
    const uint4* hp = reinterpret_cast<const uint4*>(hbuf);
#pragma unroll
    for (int k = 0; k < 16; ++k) {
      uint4 hv = hp[k];
      aA = fdot2(wa[4 * k + 0], hv.x, aA);
      aA = fdot2(wa[4 * k + 1], hv.y, aA);
      aA = fdot2(wa[4 * k + 2], hv.z, aA);
      aA = fdot2(wa[4 * k + 3], hv.w, aA);
      aB = fdot2(wb[4 * k + 0], hv.x, aB);
      aB = fdot2(wb[4 * k + 1], hv.y, aB);
      aB = fdot2(wb[4 * k + 2], hv.z, aB);
      aB = fdot2(wb[4 * k + 3], hv.w, aB);
    }

    float s = aA + aB;
    float q = aA * aA + aB * aB;
#pragma unroll
    for (int m = 1; m < 64; m <<= 1) {
      s += __shfl_xor(s, m, 64);
      q += __shfl_xor(q, m, 64);
    }
    const float mu = s * (1.f / 128.f);
    const float var = q * (1.f / 128.f) - mu * mu;
    const float rs = rsqrtf(var + 1e-5f);
    rowp[lane]      = (aA - mu) * rs * gmA + btA;
    rowp[lane + 64] = (aB - mu) * rs * gmB + btB;
    wave_lds_fence();
  }
}

// ---------------------------------------------------------------------------
extern "C" void kernel_launch(void* const* d_in, const int* in_sizes, int n_in,
                              void* d_out, int out_size, void* d_ws, size_t ws_size,
                              hipStream_t stream) {
  const float* x      = (const float*)d_in[0];
  const float* w_ih   = (const float*)d_in[1];
  const float* w_hh   = (const float*)d_in[2];
  const float* b_ih   = (const float*)d_in[3];
  const float* b_hh   = (const float*)d_in[4];
  const float* w_proj = (const float*)d_in[5];
  const float* b_proj = (const float*)d_in[6];
  const float* gamma  = (const float*)d_in[7];
  const float* beta   = (const float*)d_in[8];

  float* out = (float*)d_out;
  __half* gi = (__half*)d_ws;            // [B*T][384] f16 = 48 MB scratch

  gi_gemm<<<512, 384, 0, stream>>>(x, w_ih, b_ih, gi);
  gru_scan<<<B_, 256, 0, stream>>>(gi, w_hh, b_hh, out);
  proj_ln<<<(B_ * T_) / PROJ_ROWS, 64, 0, stream>>>(out, w_proj, b_proj, gamma, beta);
}